// Round 1
// baseline (99.778 us; speedup 1.0000x reference)
//
#include <hip/hip_runtime.h>

#define NB 64
#define NN 512
#define CI 32
#define CO 64
#define XN 68

// ---------------- K1: row stats of A ----------------
// mc[b,i] = mean_j A[b,i,j]; dg[b,i] = A[b,i,i];
// pA[b,chunk] = sum of row-sums over 64-row chunk; pD likewise for diag.
__global__ __launch_bounds__(256) void k1_rowstats(
    const float* __restrict__ A, float* __restrict__ mc, float* __restrict__ dg,
    float* __restrict__ pA, float* __restrict__ pD) {
  int b = blockIdx.x, chunk = blockIdx.y;
  int wave = threadIdx.x >> 6, lane = threadIdx.x & 63;
  const float* Ab = A + (size_t)b * NN * NN;
  __shared__ float redA[4], redD[4];
  float accR = 0.f, accD = 0.f;
  for (int t = 0; t < 16; ++t) {
    int r = chunk * 64 + wave * 16 + t;
    const float* row = Ab + (size_t)r * NN;
    float4 v0 = *(const float4*)(row + lane * 4);
    float4 v1 = *(const float4*)(row + 256 + lane * 4);
    float s = (v0.x + v0.y) + (v0.z + v0.w) + (v1.x + v1.y) + (v1.z + v1.w);
#pragma unroll
    for (int off = 32; off > 0; off >>= 1) s += __shfl_down(s, off, 64);
    if (lane == 0) {
      float d = row[r];
      mc[b * NN + r] = s * (1.0f / NN);
      dg[b * NN + r] = d;
      accR += s;
      accD += d;
    }
  }
  if (lane == 0) { redA[wave] = accR; redD[wave] = accD; }
  __syncthreads();
  if (threadIdx.x == 0) {
    pA[b * 8 + chunk] = redA[0] + redA[1] + redA[2] + redA[3];
    pD[b * 8 + chunk] = redD[0] + redD[1] + redD[2] + redD[3];
  }
}

// ---------------- K2: per-batch scalars/vectors ----------------
__global__ __launch_bounds__(256) void k2_batchstats(
    const float* __restrict__ X, const float* __restrict__ cf,
    const float* __restrict__ W1, const float* __restrict__ W2,
    const float* __restrict__ mc, const float* __restrict__ dg,
    const float* __restrict__ pA, const float* __restrict__ pD,
    float* __restrict__ meanX, float* __restrict__ vec, float* __restrict__ vplus,
    float* __restrict__ alpha1, float* __restrict__ alpha2) {
  int b = blockIdx.x, t = threadIdx.x;
  __shared__ float sc[69];
  __shared__ float smX[CI];
  __shared__ float red[256];
  if (t < 69) sc[t] = cf[t];
  const float* Xb = X + (size_t)b * NN * CI;
  int ci = t & 31, seg = t >> 5;
  float s = 0.f;
  for (int j = seg * 64; j < seg * 64 + 64; ++j) s += Xb[j * CI + ci];
  red[t] = s;
  __syncthreads();
  if (t < CI) {
    float tot = 0.f;
#pragma unroll
    for (int g = 0; g < 8; ++g) tot += red[g * 32 + t];
    float m = tot * (1.0f / NN);
    smX[t] = m;
    meanX[b * CI + t] = m;
  }
  __syncthreads();
  float sumA = 0.f, sumD = 0.f;
#pragma unroll
  for (int k = 0; k < 8; ++k) { sumA += pA[b * 8 + k]; sumD += pD[b * 8 + k]; }
  float md = sumD * (1.0f / NN);
  float ma = sumA * (1.0f / ((float)NN * (float)NN));
  float s7 = 0.f;
  for (int c2 = 0; c2 < CI; ++c2) s7 += sc[5 + CI + c2] * smX[c2];
  float cst = sc[1] * ma + sc[2] * md + s7;
  for (int i = t; i < NN; i += 256) {
    float sv = 0.f;
    for (int c2 = 0; c2 < CI; ++c2) sv += sc[5 + c2] * Xb[i * CI + c2];
    float v = sc[3] * mc[b * NN + i] + sc[4] * dg[b * NN + i] + sv;
    vec[b * NN + i] = v;
    vplus[b * NN + i] = v + cst;
  }
  if (t < CO) {
    float a1 = 0.f, a2 = 0.f;
    for (int c2 = 0; c2 < CI; ++c2) {
      a1 += W1[t * XN + CI + c2] * smX[c2];
      a2 += W2[t * XN + CI + c2] * smX[c2];
    }
    a1 += W1[t * XN + 66] * md + W1[t * XN + 67] * ma;
    a2 += W2[t * XN + 66] * md + W2[t * XN + 67] * ma;
    alpha1[b * CO + t] = a1;
    alpha2[b * CO + t] = a2;
  }
}

// ---------------- K3: X1[b,o,j] + partial S1/SV ----------------
__global__ __launch_bounds__(256) void k3_x1(
    const float* __restrict__ X, const float* __restrict__ W1,
    const float* __restrict__ mc, const float* __restrict__ dg,
    const float* __restrict__ alpha1, const float* __restrict__ vec,
    float* __restrict__ X1, float* __restrict__ S1p, float* __restrict__ SVp) {
  int b = blockIdx.x, jc = blockIdx.y;
  int t = threadIdx.x, wave = t >> 6, lane = t & 63;
  int j0 = jc * 64;
  __shared__ float sX[64][CI + 1];
  __shared__ float sW[CO][CI];
  __shared__ float sWe0[CO], sWe1[CO], sA1[CO];
  __shared__ float sMc[64], sDg[64], sVec[64];
  for (int idx = t; idx < 64 * CI; idx += 256) {
    int r = idx >> 5, c2 = idx & 31;
    sX[r][c2] = X[(size_t)b * NN * CI + (size_t)(j0 + r) * CI + c2];
    sW[r][c2] = W1[r * XN + c2];
  }
  if (t < CO) {
    sWe0[t] = W1[t * XN + 64];
    sWe1[t] = W1[t * XN + 65];
    sA1[t] = alpha1[b * CO + t];
  }
  if (t < 64) {
    sMc[t] = mc[b * NN + j0 + t];
    sDg[t] = dg[b * NN + j0 + t];
    sVec[t] = vec[b * NN + j0 + t];
  }
  __syncthreads();
  for (int m = 0; m < 16; ++m) {
    int o = wave * 16 + m;
    float s = 0.f;
#pragma unroll
    for (int c2 = 0; c2 < CI; ++c2) s += sW[o][c2] * sX[lane][c2];
    float x1 = s + sA1[o] + sWe0[o] * sMc[lane] + sWe1[o] * sDg[lane];
    X1[((size_t)b * CO + o) * NN + j0 + lane] = x1;
    float r1 = x1, r2 = sVec[lane] * x1;
#pragma unroll
    for (int off = 32; off > 0; off >>= 1) {
      r1 += __shfl_down(r1, off, 64);
      r2 += __shfl_down(r2, off, 64);
    }
    if (lane == 0) {
      S1p[((size_t)b * 8 + jc) * CO + o] = r1;
      SVp[((size_t)b * 8 + jc) * CO + o] = r2;
    }
  }
}

// ---------------- K5: per-batch GEMM + fused epilogue ----------------
// out[b,i,o] = (c0/n)*sum_j A[b,i,j]*X1[b,o,j]
//            + sum_c X[b,i,c]*W2[o,c]
//            + vplus[b,i]*S1[b,o]/n + mc[b,i]*W2[o,64] + dg[b,i]*W2[o,65]
//            + alpha2[b,o] + SV[b,o]/n
__global__ __launch_bounds__(256) void k5_gemm(
    const float* __restrict__ A, const float* __restrict__ X,
    const float* __restrict__ X1, const float* __restrict__ W2,
    const float* __restrict__ vplus, const float* __restrict__ mc,
    const float* __restrict__ dg, const float* __restrict__ S1p,
    const float* __restrict__ SVp, const float* __restrict__ alpha2,
    const float* __restrict__ cf, float* __restrict__ out) {
  int b = blockIdx.x, it = blockIdx.y;
  int t = threadIdx.x;
  int tx = t & 15, ty = t >> 4;
  int i0 = it * 64;
  __shared__ __align__(16) float As[64 * 64];  // As[jj][ii] xor-swizzled
  __shared__ __align__(16) float Bs[64 * 64];  // Bs[jj][oo] xor-swizzled
  __shared__ float sXe[64][CI + 1];
  __shared__ float sW2c[CO][CI + 1];
  __shared__ float sVp[64], sMcR[64], sDgR[64];
  __shared__ float sS1n[64], sBeta[64], sW64[64], sW65[64];

  const float* Ab = A + (size_t)b * NN * NN;
  const float* X1b = X1 + (size_t)b * CO * NN;

  for (int idx = t; idx < 64 * CI; idx += 256) {
    int r = idx >> 5, c2 = idx & 31;
    sXe[r][c2] = X[(size_t)b * NN * CI + (size_t)(i0 + r) * CI + c2];
    sW2c[r][c2] = W2[r * XN + c2];
  }
  if (t < 64) {
    sVp[t] = vplus[b * NN + i0 + t];
    sMcR[t] = mc[b * NN + i0 + t];
    sDgR[t] = dg[b * NN + i0 + t];
    float s1 = 0.f, sv = 0.f;
#pragma unroll
    for (int k = 0; k < 8; ++k) {
      s1 += S1p[((size_t)b * 8 + k) * CO + t];
      sv += SVp[((size_t)b * 8 + k) * CO + t];
    }
    sS1n[t] = s1 * (1.0f / NN);
    sBeta[t] = alpha2[b * CO + t] + sv * (1.0f / NN);
    sW64[t] = W2[t * XN + 64];
    sW65[t] = W2[t * XN + 65];
  }

  float acc[4][4] = {};
  int jj = t & 63, g = t >> 6;
  for (int jc = 0; jc < 8; ++jc) {
    int j0 = jc * 64;
    __syncthreads();
#pragma unroll
    for (int r = 0; r < 4; ++r) {
      int ii0 = g * 4 + r * 16;
      int slot = (((ii0 >> 2) ^ (jj & 15)) << 2);
      float4 va, vb;
      va.x = Ab[(size_t)(i0 + ii0 + 0) * NN + j0 + jj];
      va.y = Ab[(size_t)(i0 + ii0 + 1) * NN + j0 + jj];
      va.z = Ab[(size_t)(i0 + ii0 + 2) * NN + j0 + jj];
      va.w = Ab[(size_t)(i0 + ii0 + 3) * NN + j0 + jj];
      vb.x = X1b[(size_t)(ii0 + 0) * NN + j0 + jj];
      vb.y = X1b[(size_t)(ii0 + 1) * NN + j0 + jj];
      vb.z = X1b[(size_t)(ii0 + 2) * NN + j0 + jj];
      vb.w = X1b[(size_t)(ii0 + 3) * NN + j0 + jj];
      *(float4*)&As[jj * 64 + slot] = va;
      *(float4*)&Bs[jj * 64 + slot] = vb;
    }
    __syncthreads();
#pragma unroll 4
    for (int q = 0; q < 64; ++q) {
      int sw = q & 15;
      float4 a4 = *(const float4*)&As[q * 64 + ((ty ^ sw) << 2)];
      float4 b4 = *(const float4*)&Bs[q * 64 + ((tx ^ sw) << 2)];
      float av[4] = {a4.x, a4.y, a4.z, a4.w};
      float bv[4] = {b4.x, b4.y, b4.z, b4.w};
#pragma unroll
      for (int di = 0; di < 4; ++di)
#pragma unroll
        for (int dd = 0; dd < 4; ++dd) acc[di][dd] += av[di] * bv[dd];
    }
  }

  // epilogue
  float c0n = cf[0] * (1.0f / NN);
#pragma unroll
  for (int di = 0; di < 4; ++di)
#pragma unroll
    for (int dd = 0; dd < 4; ++dd) acc[di][dd] *= c0n;

#pragma unroll 8
  for (int c2 = 0; c2 < CI; ++c2) {
    float xv[4], wv[4];
#pragma unroll
    for (int di = 0; di < 4; ++di) xv[di] = sXe[ty * 4 + di][c2];
#pragma unroll
    for (int dd = 0; dd < 4; ++dd) wv[dd] = sW2c[tx * 4 + dd][c2];
#pragma unroll
    for (int di = 0; di < 4; ++di)
#pragma unroll
      for (int dd = 0; dd < 4; ++dd) acc[di][dd] += xv[di] * wv[dd];
  }

#pragma unroll
  for (int di = 0; di < 4; ++di) {
    int i = i0 + ty * 4 + di;
    float vp = sVp[ty * 4 + di], mcv = sMcR[ty * 4 + di], dgv = sDgR[ty * 4 + di];
    float res[4];
#pragma unroll
    for (int dd = 0; dd < 4; ++dd) {
      int o = tx * 4 + dd;
      res[dd] = acc[di][dd] + vp * sS1n[o] + mcv * sW64[o] + dgv * sW65[o] + sBeta[o];
    }
    *(float4*)&out[((size_t)b * NN + i) * CO + tx * 4] =
        make_float4(res[0], res[1], res[2], res[3]);
  }
}

extern "C" void kernel_launch(void* const* d_in, const int* in_sizes, int n_in,
                              void* d_out, int out_size, void* d_ws, size_t ws_size,
                              hipStream_t stream) {
  const float* A = (const float*)d_in[0];
  const float* X = (const float*)d_in[1];
  const float* cf = (const float*)d_in[2];
  const float* W1 = (const float*)d_in[3];
  const float* W2 = (const float*)d_in[4];
  float* out = (float*)d_out;

  float* p = (float*)d_ws;
  float* mc = p;      p += NB * NN;
  float* dg = p;      p += NB * NN;
  float* vec = p;     p += NB * NN;
  float* vplus = p;   p += NB * NN;
  float* meanX = p;   p += NB * CI;
  float* alpha1 = p;  p += NB * CO;
  float* alpha2 = p;  p += NB * CO;
  float* pA = p;      p += NB * 8;
  float* pD = p;      p += NB * 8;
  float* S1p = p;     p += NB * 8 * CO;
  float* SVp = p;     p += NB * 8 * CO;
  float* X1 = p;      p += (size_t)NB * CO * NN;

  k1_rowstats<<<dim3(NB, 8), 256, 0, stream>>>(A, mc, dg, pA, pD);
  k2_batchstats<<<NB, 256, 0, stream>>>(X, cf, W1, W2, mc, dg, pA, pD,
                                        meanX, vec, vplus, alpha1, alpha2);
  k3_x1<<<dim3(NB, 8), 256, 0, stream>>>(X, W1, mc, dg, alpha1, vec, X1, S1p, SVp);
  k5_gemm<<<dim3(NB, 8), 256, 0, stream>>>(A, X, X1, W2, vplus, mc, dg,
                                           S1p, SVp, alpha2, cf, out);
}

// Round 2
// 77.242 us; speedup vs baseline: 1.2918x; 1.2918x over previous
//
#include <hip/hip_runtime.h>
#include <hip/hip_bf16.h>

#define NB 64
#define NN 512
#define CI 32
#define CO 64
#define XN 68

typedef __attribute__((ext_vector_type(8))) short bf16x8;
typedef __attribute__((ext_vector_type(4))) float f32x4;

__device__ inline short f2bf(float f) {
  union { __hip_bfloat16 h; unsigned short u; } cv;
  cv.h = __float2bfloat16(f);
  return (short)cv.u;
}

__device__ inline bf16x8 cvt8(float4 a, float4 b) {
  bf16x8 r;
  r[0] = f2bf(a.x); r[1] = f2bf(a.y); r[2] = f2bf(a.z); r[3] = f2bf(a.w);
  r[4] = f2bf(b.x); r[5] = f2bf(b.y); r[6] = f2bf(b.z); r[7] = f2bf(b.w);
  return r;
}

// ---------------- K1: row stats of A (MLP-friendly) ----------------
__global__ __launch_bounds__(256) void k1_rowstats(
    const float* __restrict__ A, float* __restrict__ mc, float* __restrict__ dg,
    float* __restrict__ pA, float* __restrict__ pD) {
  int b = blockIdx.x, chunk = blockIdx.y;
  int w = threadIdx.x >> 6, lane = threadIdx.x & 63;
  int r0 = chunk * 64;
  const float* Ab = A + (size_t)b * NN * NN;
  __shared__ float sP[64][65];
  __shared__ float sRS[64], sD[64];
#pragma unroll
  for (int m = 0; m < 16; ++m) {
    int row = w * 16 + m;
    const float* rp = Ab + (size_t)(r0 + row) * NN;
    float4 v0 = *(const float4*)(rp + lane * 4);
    float4 v1 = *(const float4*)(rp + 256 + lane * 4);
    sP[row][lane] = (v0.x + v0.y) + (v0.z + v0.w) + (v1.x + v1.y) + (v1.z + v1.w);
  }
  __syncthreads();
  int row = threadIdx.x >> 2, q = threadIdx.x & 3;
  float s = 0.f;
#pragma unroll
  for (int k = 0; k < 16; ++k) s += sP[row][q * 16 + k];
  s += __shfl_down(s, 2);
  s += __shfl_down(s, 1);
  if (q == 0) {
    int i = r0 + row;
    float d = Ab[(size_t)i * NN + i];
    sRS[row] = s;
    sD[row] = d;
    mc[b * NN + i] = s * (1.0f / NN);
    dg[b * NN + i] = d;
  }
  __syncthreads();
  if (threadIdx.x == 0) {
    float sa = 0.f, sd = 0.f;
#pragma unroll
    for (int k = 0; k < 64; ++k) { sa += sRS[k]; sd += sD[k]; }
    pA[b * 8 + chunk] = sa;
    pD[b * 8 + chunk] = sd;
  }
}

// ---------------- K2: per-batch scalars + colv table ----------------
__global__ __launch_bounds__(256) void k2_batchstats(
    const float* __restrict__ X, const float* __restrict__ cf,
    const float* __restrict__ W1, const float* __restrict__ W2,
    const float* __restrict__ mc, const float* __restrict__ dg,
    const float* __restrict__ pA, const float* __restrict__ pD,
    float* __restrict__ vplus, float* __restrict__ a1g, float* __restrict__ colv) {
  int b = blockIdx.x, t = threadIdx.x;
  int w = t >> 6, lane = t & 63;
  __shared__ float sc[69], mX[CI], red[256], svec[NN], tC[CI], wred[12];
  __shared__ float smd, sma, scst, ssum, ssmc, ssdg;
  if (t < 69) sc[t] = cf[t];
  const float* Xb = X + (size_t)b * NN * CI;
  // phase A: meanX partials
  {
    int c = t & 31, seg = t >> 5;
    float s = 0.f;
    for (int j = seg * 64; j < seg * 64 + 64; ++j) s += Xb[j * CI + c];
    red[t] = s;
  }
  __syncthreads();
  if (t < CI) {
    float s = 0.f;
#pragma unroll
    for (int g = 0; g < 8; ++g) s += red[g * 32 + t];
    mX[t] = s * (1.0f / NN);
  }
  if (t == 64) {
    float sA = 0.f, sD = 0.f;
#pragma unroll
    for (int k = 0; k < 8; ++k) { sA += pA[b * 8 + k]; sD += pD[b * 8 + k]; }
    smd = sD * (1.0f / NN);
    sma = sA * (1.0f / ((float)NN * (float)NN));
  }
  __syncthreads();
  if (t == 0) {
    float s7 = 0.f;
    for (int c = 0; c < CI; ++c) s7 += sc[5 + CI + c] * mX[c];
    scst = sc[1] * sma + sc[2] * smd + s7;
  }
  __syncthreads();
  // phase D: vec / vplus
  for (int i = t; i < NN; i += 256) {
    float sv = 0.f;
#pragma unroll
    for (int c = 0; c < CI; ++c) sv += sc[5 + c] * Xb[i * CI + c];
    float v = sc[3] * mc[b * NN + i] + sc[4] * dg[b * NN + i] + sv;
    svec[i] = v;
    vplus[b * NN + i] = v + scst;
  }
  __syncthreads();
  // phase E: tC partials + scalar reductions
  {
    int c = t & 31, seg = t >> 5;
    float s = 0.f;
    for (int j = seg * 64; j < seg * 64 + 64; ++j) s += svec[j] * Xb[j * CI + c];
    red[t] = s;
  }
  {
    float p1 = 0.f, p2 = 0.f, p3 = 0.f;
    for (int i = t; i < NN; i += 256) {
      float v = svec[i];
      p1 += v;
      p2 += v * mc[b * NN + i];
      p3 += v * dg[b * NN + i];
    }
#pragma unroll
    for (int off = 32; off > 0; off >>= 1) {
      p1 += __shfl_down(p1, off);
      p2 += __shfl_down(p2, off);
      p3 += __shfl_down(p3, off);
    }
    if (lane == 0) { wred[w] = p1; wred[4 + w] = p2; wred[8 + w] = p3; }
  }
  __syncthreads();
  if (t < CI) {
    float s = 0.f;
#pragma unroll
    for (int g = 0; g < 8; ++g) s += red[g * 32 + t];
    tC[t] = s;
  }
  if (t == 64) {
    ssum = wred[0] + wred[1] + wred[2] + wred[3];
    ssmc = wred[4] + wred[5] + wred[6] + wred[7];
    ssdg = wred[8] + wred[9] + wred[10] + wred[11];
  }
  __syncthreads();
  // phase G: per-o outputs
  if (t < CO) {
    int o = t;
    const float* w1 = W1 + o * XN;
    const float* w2 = W2 + o * XN;
    float w1mX = 0.f, a1 = 0.f, a2 = 0.f, wt = 0.f;
#pragma unroll
    for (int c = 0; c < CI; ++c) {
      w1mX += w1[c] * mX[c];
      a1 += w1[CI + c] * mX[c];
      a2 += w2[CI + c] * mX[c];
      wt += w1[c] * tC[c];
    }
    a1 += w1[66] * smd + w1[67] * sma;
    a2 += w2[66] * smd + w2[67] * sma;
    float we0 = w1[64], we1 = w1[65];
    float S1n = w1mX + a1 + we0 * sma + we1 * smd;
    float SVn = (wt + a1 * ssum + we0 * ssmc + we1 * ssdg) * (1.0f / NN);
    a1g[b * CO + o] = a1;
    float4 cvv = make_float4(S1n, a2 + SVn, w2[64], w2[65]);
    *(float4*)&colv[(b * CO + o) * 4] = cvv;
  }
}

// ---------------- K3: X1 (bf16) ----------------
__global__ __launch_bounds__(256) void k3_x1(
    const float* __restrict__ X, const float* __restrict__ W1,
    const float* __restrict__ mc, const float* __restrict__ dg,
    const float* __restrict__ a1g, unsigned short* __restrict__ X1) {
  int b = blockIdx.x, jc = blockIdx.y;
  int t = threadIdx.x, w = t >> 6, lane = t & 63;
  int j0 = jc * 64;
  __shared__ float sX[64][CI + 1];
  __shared__ float sW[CO][CI];
  __shared__ float sWe0[CO], sWe1[CO], sA1[CO];
  __shared__ float sMc[64], sDg[64];
  for (int idx = t; idx < 64 * CI; idx += 256) {
    int r = idx >> 5, c = idx & 31;
    sX[r][c] = X[(size_t)b * NN * CI + (size_t)(j0 + r) * CI + c];
    sW[r][c] = W1[r * XN + c];
  }
  if (t < CO) {
    sWe0[t] = W1[t * XN + 64];
    sWe1[t] = W1[t * XN + 65];
    sA1[t] = a1g[b * CO + t];
  }
  if (t < 64) {
    sMc[t] = mc[b * NN + j0 + t];
    sDg[t] = dg[b * NN + j0 + t];
  }
  __syncthreads();
#pragma unroll 4
  for (int m = 0; m < 16; ++m) {
    int o = w * 16 + m;
    float s = 0.f;
#pragma unroll
    for (int c = 0; c < CI; ++c) s += sW[o][c] * sX[lane][c];
    float x1 = s + sA1[o] + sWe0[o] * sMc[lane] + sWe1[o] * sDg[lane];
    union { __hip_bfloat16 h; unsigned short u; } cv;
    cv.h = __float2bfloat16(x1);
    X1[((size_t)b * CO + o) * NN + j0 + lane] = cv.u;
  }
}

// ---------------- K5: batched MFMA GEMM + fused epilogue ----------------
// out[b,i,o] = c0/n * sum_j A[i,j]*X1[o,j]  (MFMA over K=512, bf16)
//            + sum_c X[i,c]*W2[o,c]         (one extra MFMA k-step)
//            + vplus[i]*S1n[o] + mc[i]*W2[o,64] + dg[i]*W2[o,65] + beta[o]
__global__ __launch_bounds__(256) void k5_mfma(
    const float* __restrict__ A, const unsigned short* __restrict__ X1,
    const float* __restrict__ X, const float* __restrict__ W2,
    const float* __restrict__ vplus, const float* __restrict__ mc,
    const float* __restrict__ dg, const float* __restrict__ colv,
    const float* __restrict__ cf, float* __restrict__ out) {
  int b = blockIdx.x, it = blockIdx.y;
  int w = threadIdx.x >> 6, lane = threadIdx.x & 63;
  int i0 = it * 64 + w * 16;          // this wave's 16 output rows
  int ra = lane & 15;                 // A row / B col within tile
  int kg = lane >> 4;                 // k-group (8 elems each)

  const float* Ap = A + ((size_t)b * NN + i0 + ra) * NN + kg * 8;
  const unsigned short* X1b = X1 + (size_t)b * CO * NN;

  f32x4 acc[4] = {{0.f, 0.f, 0.f, 0.f}, {0.f, 0.f, 0.f, 0.f},
                  {0.f, 0.f, 0.f, 0.f}, {0.f, 0.f, 0.f, 0.f}};

#pragma unroll 4
  for (int jt = 0; jt < 16; ++jt) {
    const float* ap = Ap + jt * 32;
    float4 a0 = *(const float4*)ap;
    float4 a1 = *(const float4*)(ap + 4);
    bf16x8 af = cvt8(a0, a1);
#pragma unroll
    for (int to = 0; to < 4; ++to) {
      bf16x8 bf = *(const bf16x8*)(X1b + (size_t)(to * 16 + ra) * NN + jt * 32 + kg * 8);
      acc[to] = __builtin_amdgcn_mfma_f32_16x16x32_bf16(af, bf, acc[to], 0, 0, 0);
    }
  }

  // scale main GEMM by c0/n
  float c0n = cf[0] * (1.0f / NN);
#pragma unroll
  for (int to = 0; to < 4; ++to)
#pragma unroll
    for (int r = 0; r < 4; ++r) acc[to][r] *= c0n;

  // fused X*W2c as one MFMA k-step (K=32)
  {
    const float* xp = X + ((size_t)b * NN + i0 + ra) * CI + kg * 8;
    float4 x0 = *(const float4*)xp;
    float4 x1 = *(const float4*)(xp + 4);
    bf16x8 xf = cvt8(x0, x1);
#pragma unroll
    for (int to = 0; to < 4; ++to) {
      const float* wp = W2 + (size_t)(to * 16 + ra) * XN + kg * 8;
      float4 w0 = *(const float4*)wp;
      float4 w1 = *(const float4*)(wp + 4);
      bf16x8 wf = cvt8(w0, w1);
      acc[to] = __builtin_amdgcn_mfma_f32_16x16x32_bf16(xf, wf, acc[to], 0, 0, 0);
    }
  }

  // rank-1 epilogue + store. D layout: col = lane&15, row = (lane>>4)*4 + reg.
  int g = lane >> 4;
  float vp[4], mcv[4], dgv[4];
#pragma unroll
  for (int r = 0; r < 4; ++r) {
    int i = i0 + g * 4 + r;
    vp[r] = vplus[b * NN + i];
    mcv[r] = mc[b * NN + i];
    dgv[r] = dg[b * NN + i];
  }
#pragma unroll
  for (int to = 0; to < 4; ++to) {
    int o = to * 16 + (lane & 15);
    float4 cv = *(const float4*)&colv[(b * CO + o) * 4];
#pragma unroll
    for (int r = 0; r < 4; ++r) {
      int i = i0 + g * 4 + r;
      float res = acc[to][r] + vp[r] * cv.x + cv.y + mcv[r] * cv.z + dgv[r] * cv.w;
      out[((size_t)b * NN + i) * CO + o] = res;
    }
  }
}

extern "C" void kernel_launch(void* const* d_in, const int* in_sizes, int n_in,
                              void* d_out, int out_size, void* d_ws, size_t ws_size,
                              hipStream_t stream) {
  const float* A = (const float*)d_in[0];
  const float* X = (const float*)d_in[1];
  const float* cf = (const float*)d_in[2];
  const float* W1 = (const float*)d_in[3];
  const float* W2 = (const float*)d_in[4];
  float* out = (float*)d_out;

  float* p = (float*)d_ws;
  float* mc = p;      p += NB * NN;
  float* dg = p;      p += NB * NN;
  float* vplus = p;   p += NB * NN;
  float* pA = p;      p += NB * 8;
  float* pD = p;      p += NB * 8;
  float* a1g = p;     p += NB * CO;
  float* colv = p;    p += NB * CO * 4;
  unsigned short* X1 = (unsigned short*)p;

  k1_rowstats<<<dim3(NB, 8), 256, 0, stream>>>(A, mc, dg, pA, pD);
  k2_batchstats<<<NB, 256, 0, stream>>>(X, cf, W1, W2, mc, dg, pA, pD,
                                        vplus, a1g, colv);
  k3_x1<<<dim3(NB, 8), 256, 0, stream>>>(X, W1, mc, dg, a1g, X1);
  k5_mfma<<<dim3(NB, 8), 256, 0, stream>>>(A, X1, X, W2, vplus, mc, dg,
                                           colv, cf, out);
}

// Round 3
// 75.415 us; speedup vs baseline: 1.3231x; 1.0242x over previous
//
#include <hip/hip_runtime.h>
#include <hip/hip_bf16.h>

#define NB 64
#define NN 512
#define CI 32
#define CO 64
#define XN 68

typedef __attribute__((ext_vector_type(8))) short bf16x8;
typedef __attribute__((ext_vector_type(4))) float f32x4;

__device__ inline short f2bf(float f) {
  union { __hip_bfloat16 h; unsigned short u; } cv;
  cv.h = __float2bfloat16(f);
  return (short)cv.u;
}

__device__ inline bf16x8 cvt8(float4 a, float4 b) {
  bf16x8 r;
  r[0] = f2bf(a.x); r[1] = f2bf(a.y); r[2] = f2bf(a.z); r[3] = f2bf(a.w);
  r[4] = f2bf(b.x); r[5] = f2bf(b.y); r[6] = f2bf(b.z); r[7] = f2bf(b.w);
  return r;
}

__device__ inline bf16x8 cvt8s(float4 a, float4 b, float s) {
  bf16x8 r;
  r[0] = f2bf(a.x * s); r[1] = f2bf(a.y * s); r[2] = f2bf(a.z * s); r[3] = f2bf(a.w * s);
  r[4] = f2bf(b.x * s); r[5] = f2bf(b.y * s); r[6] = f2bf(b.z * s); r[7] = f2bf(b.w * s);
  return r;
}

// ---------------- K1: A row stats. grid (NB, 32), 16 rows/block ----------------
__global__ __launch_bounds__(256) void k1_rowstats(
    const float* __restrict__ A, float* __restrict__ mc, float* __restrict__ dg,
    float* __restrict__ pA, float* __restrict__ pD) {
  int b = blockIdx.x, ch = blockIdx.y;
  int t = threadIdx.x, w = t >> 6, lane = t & 63;
  int r0 = ch * 16;
  const float* Ab = A + (size_t)b * NN * NN;
  __shared__ float wsum[4];
  __shared__ float sD[16];
  float4 v0[4], v1[4];
#pragma unroll
  for (int m = 0; m < 4; ++m) {
    const float* rp = Ab + (size_t)(r0 + w * 4 + m) * NN;
    v0[m] = *(const float4*)(rp + lane * 4);
    v1[m] = *(const float4*)(rp + 256 + lane * 4);
  }
  float accR = 0.f;
#pragma unroll
  for (int m = 0; m < 4; ++m) {
    float s = (v0[m].x + v0[m].y) + (v0[m].z + v0[m].w) +
              (v1[m].x + v1[m].y) + (v1[m].z + v1[m].w);
#pragma unroll
    for (int off = 1; off < 64; off <<= 1) s += __shfl_xor(s, off, 64);
    if (lane == 0) mc[b * NN + r0 + w * 4 + m] = s * (1.0f / NN);
    accR += s;
  }
  if (lane == 0) wsum[w] = accR;
  if (t < 16) {
    float d = Ab[(size_t)(r0 + t) * NN + r0 + t];
    dg[b * NN + r0 + t] = d;
    sD[t] = d;
  }
  __syncthreads();
  if (t == 0) {
    pA[b * 32 + ch] = wsum[0] + wsum[1] + wsum[2] + wsum[3];
    float sd = 0.f;
#pragma unroll
    for (int k = 0; k < 16; ++k) sd += sD[k];
    pD[b * 32 + ch] = sd;
  }
}

// ---------------- K23: per-batch scalars + colv + X1 (bf16, MFMA) ----------------
__global__ __launch_bounds__(256) void k23_batch(
    const float* __restrict__ X, const float* __restrict__ cf,
    const float* __restrict__ W1, const float* __restrict__ W2,
    const float* __restrict__ mc, const float* __restrict__ dg,
    const float* __restrict__ pA, const float* __restrict__ pD,
    float* __restrict__ vplus, float* __restrict__ colv,
    unsigned short* __restrict__ X1) {
  int b = blockIdx.x, t = threadIdx.x;
  int w = t >> 6, lane = t & 63;
  __shared__ float sc[69], mX[CI], red[256], svec[NN], tC[CI], wred[12], sA1[CO];
  __shared__ float smd, sma, scst, ssum, ssmc, ssdg;
  if (t < 69) sc[t] = cf[t];
  const float* Xb = X + (size_t)b * NN * CI;
  // phase A: meanX partials
  {
    int c = t & 31, seg = t >> 5;
    float s = 0.f;
    for (int j = seg * 64; j < seg * 64 + 64; ++j) s += Xb[j * CI + c];
    red[t] = s;
  }
  __syncthreads();
  if (t < CI) {
    float s = 0.f;
#pragma unroll
    for (int g = 0; g < 8; ++g) s += red[g * 32 + t];
    mX[t] = s * (1.0f / NN);
  }
  if (t == 64) {
    float sA = 0.f, sD = 0.f;
#pragma unroll
    for (int k = 0; k < 32; ++k) { sA += pA[b * 32 + k]; sD += pD[b * 32 + k]; }
    smd = sD * (1.0f / NN);
    sma = sA * (1.0f / ((float)NN * (float)NN));
  }
  __syncthreads();
  if (t == 0) {
    float s7 = 0.f;
    for (int c = 0; c < CI; ++c) s7 += sc[5 + CI + c] * mX[c];
    scst = sc[1] * sma + sc[2] * smd + s7;
  }
  __syncthreads();
  // phase D: vec / vplus
  for (int i = t; i < NN; i += 256) {
    float sv = 0.f;
#pragma unroll
    for (int c = 0; c < CI; ++c) sv += sc[5 + c] * Xb[i * CI + c];
    float v = sc[3] * mc[b * NN + i] + sc[4] * dg[b * NN + i] + sv;
    svec[i] = v;
    vplus[b * NN + i] = v + scst;
  }
  __syncthreads();
  // phase E: tC partials + scalar reductions
  {
    int c = t & 31, seg = t >> 5;
    float s = 0.f;
    for (int j = seg * 64; j < seg * 64 + 64; ++j) s += svec[j] * Xb[j * CI + c];
    red[t] = s;
  }
  {
    float p1 = 0.f, p2 = 0.f, p3 = 0.f;
    for (int i = t; i < NN; i += 256) {
      float v = svec[i];
      p1 += v;
      p2 += v * mc[b * NN + i];
      p3 += v * dg[b * NN + i];
    }
#pragma unroll
    for (int off = 32; off > 0; off >>= 1) {
      p1 += __shfl_down(p1, off);
      p2 += __shfl_down(p2, off);
      p3 += __shfl_down(p3, off);
    }
    if (lane == 0) { wred[w] = p1; wred[4 + w] = p2; wred[8 + w] = p3; }
  }
  __syncthreads();
  if (t < CI) {
    float s = 0.f;
#pragma unroll
    for (int g = 0; g < 8; ++g) s += red[g * 32 + t];
    tC[t] = s;
  }
  if (t == 64) {
    ssum = wred[0] + wred[1] + wred[2] + wred[3];
    ssmc = wred[4] + wred[5] + wred[6] + wred[7];
    ssdg = wred[8] + wred[9] + wred[10] + wred[11];
  }
  __syncthreads();
  // phase G: per-o scalars
  if (t < CO) {
    int o = t;
    const float* w1 = W1 + o * XN;
    const float* w2 = W2 + o * XN;
    float w1mX = 0.f, a1 = 0.f, a2 = 0.f, wt = 0.f;
#pragma unroll
    for (int c = 0; c < CI; ++c) {
      w1mX += w1[c] * mX[c];
      a1 += w1[CI + c] * mX[c];
      a2 += w2[CI + c] * mX[c];
      wt += w1[c] * tC[c];
    }
    a1 += w1[66] * smd + w1[67] * sma;
    a2 += w2[66] * smd + w2[67] * sma;
    float we0 = w1[64], we1 = w1[65];
    float S1n = w1mX + a1 + we0 * sma + we1 * smd;
    float SVn = (wt + a1 * ssum + we0 * ssmc + we1 * ssdg) * (1.0f / NN);
    sA1[o] = a1;
    float4 cvv = make_float4(S1n, a2 + SVn, w2[64], w2[65]);
    *(float4*)&colv[(b * CO + o) * 4] = cvv;
  }
  __syncthreads();
  // phase H: X1[o,j] = Y + a1[o] + we0[o]*mc[j] + we1[o]*dg[j]   (MFMA)
  {
    int ra = lane & 15, kg = lane >> 4, g = lane >> 4;
    bf16x8 wfrag[4];
    float ao[4], e0[4], e1[4];
#pragma unroll
    for (int to = 0; to < 4; ++to) {
      int o = to * 16 + ra;
      const float* wp = W1 + o * XN + kg * 8;
      wfrag[to] = cvt8(*(const float4*)wp, *(const float4*)(wp + 4));
      int ol = to * 16 + (lane & 15);
      ao[to] = sA1[ol];
      e0[to] = W1[ol * XN + 64];
      e1[to] = W1[ol * XN + 65];
    }
#pragma unroll
    for (int jj = 0; jj < 8; ++jj) {
      int j0 = (w * 8 + jj) * 16;
      const float* xp = Xb + (size_t)(j0 + ra) * CI + kg * 8;
      bf16x8 xf = cvt8(*(const float4*)xp, *(const float4*)(xp + 4));
      float4 mcv = *(const float4*)&mc[b * NN + j0 + g * 4];
      float4 dgv = *(const float4*)&dg[b * NN + j0 + g * 4];
      float mcr[4] = {mcv.x, mcv.y, mcv.z, mcv.w};
      float dgr[4] = {dgv.x, dgv.y, dgv.z, dgv.w};
#pragma unroll
      for (int to = 0; to < 4; ++to) {
        f32x4 zero = {0.f, 0.f, 0.f, 0.f};
        f32x4 d = __builtin_amdgcn_mfma_f32_16x16x32_bf16(xf, wfrag[to], zero, 0, 0, 0);
        union { unsigned short u[4]; uint2 v; } pk;
#pragma unroll
        for (int r = 0; r < 4; ++r) {
          float val = d[r] + ao[to] + e0[to] * mcr[r] + e1[to] * dgr[r];
          pk.u[r] = (unsigned short)f2bf(val);
        }
        *(uint2*)(X1 + ((size_t)b * CO + to * 16 + (lane & 15)) * NN + j0 + g * 4) = pk.v;
      }
    }
  }
}

// ---------------- K5: batched MFMA GEMM, K split across waves ----------------
// grid (NB, 16), 512 threads = 8 waves. Block: 32 i-rows x 64 o.
// wave (ia = w&1, q = w>>1): rows [i0+ia*16, +16), K quarter q (128 k).
// A pre-scaled by c0/n before bf16 cvt; W2 k-step added by q==0 waves.
__global__ __launch_bounds__(512) void k5_mfma(
    const float* __restrict__ A, const unsigned short* __restrict__ X1,
    const float* __restrict__ X, const float* __restrict__ W2,
    const float* __restrict__ vplus, const float* __restrict__ mc,
    const float* __restrict__ dg, const float* __restrict__ colv,
    const float* __restrict__ cf, float* __restrict__ out) {
  int b = blockIdx.x, ic = blockIdx.y;
  int t = threadIdx.x, w = t >> 6, lane = t & 63;
  int ia = w & 1, q = w >> 1;
  int ra = lane & 15, kg = lane >> 4, g = lane >> 4;
  int i0 = ic * 32;
  __shared__ float sAcc[4 * 32 * 68];

  float c0n = cf[0] * (1.0f / NN);
  const float* Arow = A + ((size_t)(b * NN + i0 + ia * 16 + ra)) * NN;
  const unsigned short* X1b = X1 + (size_t)b * CO * NN;

  f32x4 acc[4] = {{0.f, 0.f, 0.f, 0.f}, {0.f, 0.f, 0.f, 0.f},
                  {0.f, 0.f, 0.f, 0.f}, {0.f, 0.f, 0.f, 0.f}};

#pragma unroll
  for (int jt = 0; jt < 4; ++jt) {
    int kb = q * 128 + jt * 32 + kg * 8;
    float4 a0 = *(const float4*)(Arow + kb);
    float4 a1 = *(const float4*)(Arow + kb + 4);
    bf16x8 af = cvt8s(a0, a1, c0n);
#pragma unroll
    for (int to = 0; to < 4; ++to) {
      bf16x8 bf = *(const bf16x8*)(X1b + (size_t)(to * 16 + ra) * NN + kb);
      acc[to] = __builtin_amdgcn_mfma_f32_16x16x32_bf16(af, bf, acc[to], 0, 0, 0);
    }
  }

  if (q == 0) {  // fused X*W2c k-step (unscaled)
    const float* xp = X + (size_t)(b * NN + i0 + ia * 16 + ra) * CI + kg * 8;
    bf16x8 xf = cvt8(*(const float4*)xp, *(const float4*)(xp + 4));
#pragma unroll
    for (int to = 0; to < 4; ++to) {
      const float* wp = W2 + (size_t)(to * 16 + ra) * XN + kg * 8;
      bf16x8 wf = cvt8(*(const float4*)wp, *(const float4*)(wp + 4));
      acc[to] = __builtin_amdgcn_mfma_f32_16x16x32_bf16(xf, wf, acc[to], 0, 0, 0);
    }
  }

  // store partials: sAcc[q][i_local 32][o 64 (pad 68)]
#pragma unroll
  for (int to = 0; to < 4; ++to)
#pragma unroll
    for (int r = 0; r < 4; ++r)
      sAcc[(q * 32 + ia * 16 + g * 4 + r) * 68 + to * 16 + (lane & 15)] = acc[to][r];
  __syncthreads();

  // reduce + epilogue: thread t -> row i = t>>4, cols o4 = (t&15)*4
  {
    int i = t >> 4, o4 = (t & 15) * 4;
    f32x4 s = {0.f, 0.f, 0.f, 0.f};
#pragma unroll
    for (int qq = 0; qq < 4; ++qq) s += *(const f32x4*)&sAcc[(qq * 32 + i) * 68 + o4];
    float vp = vplus[b * NN + i0 + i];
    float mcv = mc[b * NN + i0 + i];
    float dgv = dg[b * NN + i0 + i];
    float4 res;
    {
      float4 cv0 = *(const float4*)&colv[(b * CO + o4 + 0) * 4];
      float4 cv1 = *(const float4*)&colv[(b * CO + o4 + 1) * 4];
      float4 cv2 = *(const float4*)&colv[(b * CO + o4 + 2) * 4];
      float4 cv3 = *(const float4*)&colv[(b * CO + o4 + 3) * 4];
      res.x = s[0] + vp * cv0.x + cv0.y + mcv * cv0.z + dgv * cv0.w;
      res.y = s[1] + vp * cv1.x + cv1.y + mcv * cv1.z + dgv * cv1.w;
      res.z = s[2] + vp * cv2.x + cv2.y + mcv * cv2.z + dgv * cv2.w;
      res.w = s[3] + vp * cv3.x + cv3.y + mcv * cv3.z + dgv * cv3.w;
    }
    *(float4*)&out[((size_t)(b * NN + i0 + i)) * CO + o4] = res;
  }
}

extern "C" void kernel_launch(void* const* d_in, const int* in_sizes, int n_in,
                              void* d_out, int out_size, void* d_ws, size_t ws_size,
                              hipStream_t stream) {
  const float* A = (const float*)d_in[0];
  const float* X = (const float*)d_in[1];
  const float* cf = (const float*)d_in[2];
  const float* W1 = (const float*)d_in[3];
  const float* W2 = (const float*)d_in[4];
  float* out = (float*)d_out;

  float* p = (float*)d_ws;
  float* mc = p;      p += NB * NN;
  float* dg = p;      p += NB * NN;
  float* vplus = p;   p += NB * NN;
  float* pA = p;      p += NB * 32;
  float* pD = p;      p += NB * 32;
  float* colv = p;    p += NB * CO * 4;
  unsigned short* X1 = (unsigned short*)p;

  k1_rowstats<<<dim3(NB, 32), 256, 0, stream>>>(A, mc, dg, pA, pD);
  k23_batch<<<NB, 256, 0, stream>>>(X, cf, W1, W2, mc, dg, pA, pD,
                                    vplus, colv, X1);
  k5_mfma<<<dim3(NB, 16), 512, 0, stream>>>(A, X1, X, W2, vplus, mc, dg,
                                            colv, cf, out);
}

// Round 4
// 56.545 us; speedup vs baseline: 1.7646x; 1.3337x over previous
//
#include <hip/hip_runtime.h>
#include <hip/hip_bf16.h>

#define NB 64
#define NN 512
#define CI 32
#define CO 64
#define XN 68

typedef __attribute__((ext_vector_type(8))) short bf16x8;
typedef __attribute__((ext_vector_type(4))) float f32x4;

__device__ inline short f2bf(float f) {
  union { __hip_bfloat16 h; unsigned short u; } cv;
  cv.h = __float2bfloat16(f);
  return (short)cv.u;
}

__device__ inline bf16x8 cvt8(float4 a, float4 b) {
  bf16x8 r;
  r[0] = f2bf(a.x); r[1] = f2bf(a.y); r[2] = f2bf(a.z); r[3] = f2bf(a.w);
  r[4] = f2bf(b.x); r[5] = f2bf(b.y); r[6] = f2bf(b.z); r[7] = f2bf(b.w);
  return r;
}

__device__ inline bf16x8 cvt8s(float4 a, float4 b, float s) {
  bf16x8 r;
  r[0] = f2bf(a.x * s); r[1] = f2bf(a.y * s); r[2] = f2bf(a.z * s); r[3] = f2bf(a.w * s);
  r[4] = f2bf(b.x * s); r[5] = f2bf(b.y * s); r[6] = f2bf(b.z * s); r[7] = f2bf(b.w * s);
  return r;
}

// ---------------- K1: A row stats. grid (NB, 32), 16 rows/block ----------------
__global__ __launch_bounds__(256) void k1_rowstats(
    const float* __restrict__ A, float* __restrict__ mc, float* __restrict__ dg,
    float* __restrict__ pA, float* __restrict__ pD) {
  int b = blockIdx.x, ch = blockIdx.y;
  int t = threadIdx.x, w = t >> 6, lane = t & 63;
  int r0 = ch * 16;
  const float* Ab = A + (size_t)b * NN * NN;
  __shared__ float wsum[4];
  __shared__ float sD[16];
  float4 v0[4], v1[4];
#pragma unroll
  for (int m = 0; m < 4; ++m) {
    const float* rp = Ab + (size_t)(r0 + w * 4 + m) * NN;
    v0[m] = *(const float4*)(rp + lane * 4);
    v1[m] = *(const float4*)(rp + 256 + lane * 4);
  }
  float accR = 0.f;
#pragma unroll
  for (int m = 0; m < 4; ++m) {
    float s = (v0[m].x + v0[m].y) + (v0[m].z + v0[m].w) +
              (v1[m].x + v1[m].y) + (v1[m].z + v1[m].w);
#pragma unroll
    for (int off = 1; off < 64; off <<= 1) s += __shfl_xor(s, off, 64);
    if (lane == 0) mc[b * NN + r0 + w * 4 + m] = s * (1.0f / NN);
    accR += s;
  }
  if (lane == 0) wsum[w] = accR;
  if (t < 16) {
    float d = Ab[(size_t)(r0 + t) * NN + r0 + t];
    dg[b * NN + r0 + t] = d;
    sD[t] = d;
  }
  __syncthreads();
  if (t == 0) {
    pA[b * 32 + ch] = wsum[0] + wsum[1] + wsum[2] + wsum[3];
    float sd = 0.f;
#pragma unroll
    for (int k = 0; k < 16; ++k) sd += sD[k];
    pD[b * 32 + ch] = sd;
  }
}

// ---------------- K2a: per-128-row partials. grid (NB, 4) ----------------
// thread pair per row: h = t&1 owns cols h*16..h*16+15 (in regs, one pass).
__global__ __launch_bounds__(256) void k2a_partials(
    const float* __restrict__ X, const float* __restrict__ cf,
    const float* __restrict__ mc, const float* __restrict__ dg,
    float* __restrict__ vec, float* __restrict__ pmX, float* __restrict__ ptC,
    float* __restrict__ pS) {
  int b = blockIdx.x, yc = blockIdx.y;
  int t = threadIdx.x, w = t >> 6, lane = t & 63;
  int h = t & 1;
  int j = yc * 128 + (t >> 1);
  __shared__ float sMX[4][32], sTC[4][32], sP[4][3];

  const float* xp = X + ((size_t)b * NN + j) * CI + h * 16;
  float4 x4[4];
#pragma unroll
  for (int k = 0; k < 4; ++k) x4[k] = *(const float4*)(xp + k * 4);

  float c3 = cf[3], c4 = cf[4];
  float sv_part = 0.f;
#pragma unroll
  for (int k = 0; k < 4; ++k) {
    int c0 = 5 + h * 16 + k * 4;
    sv_part += cf[c0] * x4[k].x + cf[c0 + 1] * x4[k].y +
               cf[c0 + 2] * x4[k].z + cf[c0 + 3] * x4[k].w;
  }
  float sv = sv_part + __shfl_xor(sv_part, 1, 64);
  float mcj = mc[b * NN + j], dgj = dg[b * NN + j];
  float svec = fmaf(c3, mcj, fmaf(c4, dgj, sv));
  if (h == 0) vec[b * NN + j] = svec;

  float p1 = (h == 0) ? svec : 0.f;
  float p2 = (h == 0) ? svec * mcj : 0.f;
  float p3 = (h == 0) ? svec * dgj : 0.f;
  float4 tc4[4];
#pragma unroll
  for (int k = 0; k < 4; ++k) {
    tc4[k].x = svec * x4[k].x; tc4[k].y = svec * x4[k].y;
    tc4[k].z = svec * x4[k].z; tc4[k].w = svec * x4[k].w;
  }
  // butterfly over row-lanes (strides 2..32); halves stay separate
#pragma unroll
  for (int off = 2; off < 64; off <<= 1) {
#pragma unroll
    for (int k = 0; k < 4; ++k) {
      x4[k].x += __shfl_xor(x4[k].x, off, 64);
      x4[k].y += __shfl_xor(x4[k].y, off, 64);
      x4[k].z += __shfl_xor(x4[k].z, off, 64);
      x4[k].w += __shfl_xor(x4[k].w, off, 64);
      tc4[k].x += __shfl_xor(tc4[k].x, off, 64);
      tc4[k].y += __shfl_xor(tc4[k].y, off, 64);
      tc4[k].z += __shfl_xor(tc4[k].z, off, 64);
      tc4[k].w += __shfl_xor(tc4[k].w, off, 64);
    }
    p1 += __shfl_xor(p1, off, 64);
    p2 += __shfl_xor(p2, off, 64);
    p3 += __shfl_xor(p3, off, 64);
  }
  if (lane < 2) {
#pragma unroll
    for (int k = 0; k < 4; ++k) {
      *(float4*)&sMX[w][lane * 16 + k * 4] = x4[k];
      *(float4*)&sTC[w][lane * 16 + k * 4] = tc4[k];
    }
    if (lane == 0) { sP[w][0] = p1; sP[w][1] = p2; sP[w][2] = p3; }
  }
  __syncthreads();
  if (t < 32) {
    pmX[(b * 4 + yc) * 32 + t] = sMX[0][t] + sMX[1][t] + sMX[2][t] + sMX[3][t];
    ptC[(b * 4 + yc) * 32 + t] = sTC[0][t] + sTC[1][t] + sTC[2][t] + sTC[3][t];
  } else if (t < 35) {
    int k = t - 32;
    pS[(b * 4 + yc) * 3 + k] = sP[0][k] + sP[1][k] + sP[2][k] + sP[3][k];
  }
}

// ---------------- K2b: per-batch finalize. grid (NB) ----------------
__global__ __launch_bounds__(256) void k2b_finalize(
    const float* __restrict__ cf, const float* __restrict__ W1,
    const float* __restrict__ W2, const float* __restrict__ pA,
    const float* __restrict__ pD, const float* __restrict__ pmX,
    const float* __restrict__ ptC, const float* __restrict__ pS,
    const float* __restrict__ vec, float* __restrict__ vplus,
    float* __restrict__ colv, float* __restrict__ a1g) {
  int b = blockIdx.x, t = threadIdx.x;
  __shared__ float mX[CI], tC[CI];
  __shared__ float smd, sma, scst, ssum, ssmc, ssdg;
  if (t < 32) {
    float s1 = 0.f, s2 = 0.f;
#pragma unroll
    for (int y = 0; y < 4; ++y) {
      s1 += pmX[(b * 4 + y) * 32 + t];
      s2 += ptC[(b * 4 + y) * 32 + t];
    }
    mX[t] = s1 * (1.0f / NN);
    tC[t] = s2;
  } else if (t == 32) {
    float sA = 0.f, sD = 0.f;
#pragma unroll
    for (int k = 0; k < 32; ++k) { sA += pA[b * 32 + k]; sD += pD[b * 32 + k]; }
    smd = sD * (1.0f / NN);
    sma = sA * (1.0f / ((float)NN * (float)NN));
  } else if (t == 33) {
    float s1 = 0.f, s2 = 0.f, s3 = 0.f;
#pragma unroll
    for (int y = 0; y < 4; ++y) {
      s1 += pS[(b * 4 + y) * 3 + 0];
      s2 += pS[(b * 4 + y) * 3 + 1];
      s3 += pS[(b * 4 + y) * 3 + 2];
    }
    ssum = s1; ssmc = s2; ssdg = s3;
  }
  __syncthreads();
  if (t == 0) {
    float s7 = 0.f;
    for (int c = 0; c < CI; ++c) s7 += cf[5 + CI + c] * mX[c];
    scst = cf[1] * sma + cf[2] * smd + s7;
  }
  __syncthreads();
  vplus[b * NN + t] = vec[b * NN + t] + scst;
  vplus[b * NN + 256 + t] = vec[b * NN + 256 + t] + scst;
  if (t < CO) {
    int o = t;
    const float* w1 = W1 + o * XN;
    const float* w2 = W2 + o * XN;
    float w1mX = 0.f, a1 = 0.f, a2 = 0.f, wt = 0.f;
#pragma unroll
    for (int c = 0; c < CI; ++c) {
      w1mX += w1[c] * mX[c];
      a1 += w1[CI + c] * mX[c];
      a2 += w2[CI + c] * mX[c];
      wt += w1[c] * tC[c];
    }
    a1 += w1[66] * smd + w1[67] * sma;
    a2 += w2[66] * smd + w2[67] * sma;
    float we0 = w1[64], we1 = w1[65];
    float S1n = w1mX + a1 + we0 * sma + we1 * smd;
    float SVn = (wt + a1 * ssum + we0 * ssmc + we1 * ssdg) * (1.0f / NN);
    a1g[b * CO + o] = a1;
    float4 cvv = make_float4(S1n, a2 + SVn, w2[64], w2[65]);
    *(float4*)&colv[(b * CO + o) * 4] = cvv;
  }
}

// ---------------- K3: X1 (bf16) via MFMA. grid (NB, 4) ----------------
__global__ __launch_bounds__(256) void k3_x1(
    const float* __restrict__ X, const float* __restrict__ W1,
    const float* __restrict__ mc, const float* __restrict__ dg,
    const float* __restrict__ a1g, unsigned short* __restrict__ X1) {
  int b = blockIdx.x, yc = blockIdx.y;
  int t = threadIdx.x, w = t >> 6, lane = t & 63;
  int ra = lane & 15, kg = lane >> 4, g = lane >> 4;
  const float* Xb = X + (size_t)b * NN * CI;

  bf16x8 wfrag[4];
  float ao[4], e0[4], e1[4];
#pragma unroll
  for (int to = 0; to < 4; ++to) {
    int o = to * 16 + ra;
    const float* wp = W1 + o * XN + kg * 8;
    wfrag[to] = cvt8(*(const float4*)wp, *(const float4*)(wp + 4));
    int ol = to * 16 + ra;
    ao[to] = a1g[b * CO + ol];
    e0[to] = W1[ol * XN + 64];
    e1[to] = W1[ol * XN + 65];
  }
#pragma unroll
  for (int jj = 0; jj < 2; ++jj) {
    int j0 = yc * 128 + w * 32 + jj * 16;
    const float* xp = Xb + (size_t)(j0 + ra) * CI + kg * 8;
    bf16x8 xf = cvt8(*(const float4*)xp, *(const float4*)(xp + 4));
    float4 mcv = *(const float4*)&mc[b * NN + j0 + g * 4];
    float4 dgv = *(const float4*)&dg[b * NN + j0 + g * 4];
    float mcr[4] = {mcv.x, mcv.y, mcv.z, mcv.w};
    float dgr[4] = {dgv.x, dgv.y, dgv.z, dgv.w};
#pragma unroll
    for (int to = 0; to < 4; ++to) {
      f32x4 zero = {0.f, 0.f, 0.f, 0.f};
      f32x4 d = __builtin_amdgcn_mfma_f32_16x16x32_bf16(xf, wfrag[to], zero, 0, 0, 0);
      union { unsigned short u[4]; uint2 v; } pk;
#pragma unroll
      for (int r = 0; r < 4; ++r) {
        float val = d[r] + ao[to] + e0[to] * mcr[r] + e1[to] * dgr[r];
        pk.u[r] = (unsigned short)f2bf(val);
      }
      *(uint2*)(X1 + ((size_t)b * CO + to * 16 + ra) * NN + j0 + g * 4) = pk.v;
    }
  }
}

// ---------------- K5: batched MFMA GEMM, K split across waves ----------------
__global__ __launch_bounds__(512) void k5_mfma(
    const float* __restrict__ A, const unsigned short* __restrict__ X1,
    const float* __restrict__ X, const float* __restrict__ W2,
    const float* __restrict__ vplus, const float* __restrict__ mc,
    const float* __restrict__ dg, const float* __restrict__ colv,
    const float* __restrict__ cf, float* __restrict__ out) {
  int b = blockIdx.x, ic = blockIdx.y;
  int t = threadIdx.x, w = t >> 6, lane = t & 63;
  int ia = w & 1, q = w >> 1;
  int ra = lane & 15, kg = lane >> 4, g = lane >> 4;
  int i0 = ic * 32;
  __shared__ float sAcc[4 * 32 * 68];

  float c0n = cf[0] * (1.0f / NN);
  const float* Arow = A + ((size_t)(b * NN + i0 + ia * 16 + ra)) * NN;
  const unsigned short* X1b = X1 + (size_t)b * CO * NN;

  f32x4 acc[4] = {{0.f, 0.f, 0.f, 0.f}, {0.f, 0.f, 0.f, 0.f},
                  {0.f, 0.f, 0.f, 0.f}, {0.f, 0.f, 0.f, 0.f}};

#pragma unroll
  for (int jt = 0; jt < 4; ++jt) {
    int kb = q * 128 + jt * 32 + kg * 8;
    float4 a0 = *(const float4*)(Arow + kb);
    float4 a1 = *(const float4*)(Arow + kb + 4);
    bf16x8 af = cvt8s(a0, a1, c0n);
#pragma unroll
    for (int to = 0; to < 4; ++to) {
      bf16x8 bf = *(const bf16x8*)(X1b + (size_t)(to * 16 + ra) * NN + kb);
      acc[to] = __builtin_amdgcn_mfma_f32_16x16x32_bf16(af, bf, acc[to], 0, 0, 0);
    }
  }

  if (q == 0) {  // fused X*W2c k-step (unscaled)
    const float* xp = X + (size_t)(b * NN + i0 + ia * 16 + ra) * CI + kg * 8;
    bf16x8 xf = cvt8(*(const float4*)xp, *(const float4*)(xp + 4));
#pragma unroll
    for (int to = 0; to < 4; ++to) {
      const float* wp = W2 + (size_t)(to * 16 + ra) * XN + kg * 8;
      bf16x8 wf = cvt8(*(const float4*)wp, *(const float4*)(wp + 4));
      acc[to] = __builtin_amdgcn_mfma_f32_16x16x32_bf16(xf, wf, acc[to], 0, 0, 0);
    }
  }

#pragma unroll
  for (int to = 0; to < 4; ++to)
#pragma unroll
    for (int r = 0; r < 4; ++r)
      sAcc[(q * 32 + ia * 16 + g * 4 + r) * 68 + to * 16 + ra] = acc[to][r];
  __syncthreads();

  {
    int i = t >> 4, o4 = (t & 15) * 4;
    f32x4 s = {0.f, 0.f, 0.f, 0.f};
#pragma unroll
    for (int qq = 0; qq < 4; ++qq) s += *(const f32x4*)&sAcc[(qq * 32 + i) * 68 + o4];
    float vp = vplus[b * NN + i0 + i];
    float mcv = mc[b * NN + i0 + i];
    float dgv = dg[b * NN + i0 + i];
    float4 res;
    {
      float4 cv0 = *(const float4*)&colv[(b * CO + o4 + 0) * 4];
      float4 cv1 = *(const float4*)&colv[(b * CO + o4 + 1) * 4];
      float4 cv2 = *(const float4*)&colv[(b * CO + o4 + 2) * 4];
      float4 cv3 = *(const float4*)&colv[(b * CO + o4 + 3) * 4];
      res.x = s[0] + vp * cv0.x + cv0.y + mcv * cv0.z + dgv * cv0.w;
      res.y = s[1] + vp * cv1.x + cv1.y + mcv * cv1.z + dgv * cv1.w;
      res.z = s[2] + vp * cv2.x + cv2.y + mcv * cv2.z + dgv * cv2.w;
      res.w = s[3] + vp * cv3.x + cv3.y + mcv * cv3.z + dgv * cv3.w;
    }
    *(float4*)&out[((size_t)(b * NN + i0 + i)) * CO + o4] = res;
  }
}

extern "C" void kernel_launch(void* const* d_in, const int* in_sizes, int n_in,
                              void* d_out, int out_size, void* d_ws, size_t ws_size,
                              hipStream_t stream) {
  const float* A = (const float*)d_in[0];
  const float* X = (const float*)d_in[1];
  const float* cf = (const float*)d_in[2];
  const float* W1 = (const float*)d_in[3];
  const float* W2 = (const float*)d_in[4];
  float* out = (float*)d_out;

  float* p = (float*)d_ws;
  float* mc = p;      p += NB * NN;
  float* dg = p;      p += NB * NN;
  float* vec = p;     p += NB * NN;
  float* vplus = p;   p += NB * NN;
  float* pA = p;      p += NB * 32;
  float* pD = p;      p += NB * 32;
  float* pmX = p;     p += NB * 4 * 32;
  float* ptC = p;     p += NB * 4 * 32;
  float* pS = p;      p += NB * 4 * 3;
  float* colv = p;    p += NB * CO * 4;
  float* a1g = p;     p += NB * CO;
  unsigned short* X1 = (unsigned short*)p;

  k1_rowstats<<<dim3(NB, 32), 256, 0, stream>>>(A, mc, dg, pA, pD);
  k2a_partials<<<dim3(NB, 4), 256, 0, stream>>>(X, cf, mc, dg, vec, pmX, ptC, pS);
  k2b_finalize<<<NB, 256, 0, stream>>>(cf, W1, W2, pA, pD, pmX, ptC, pS,
                                       vec, vplus, colv, a1g);
  k3_x1<<<dim3(NB, 4), 256, 0, stream>>>(X, W1, mc, dg, a1g, X1);
  k5_mfma<<<dim3(NB, 16), 512, 0, stream>>>(A, X1, X, W2, vplus, mc, dg,
                                            colv, cf, out);
}

// Round 5
// 55.710 us; speedup vs baseline: 1.7910x; 1.0150x over previous
//
#include <hip/hip_runtime.h>
#include <hip/hip_bf16.h>

#define NB 64
#define NN 512
#define CI 32
#define CO 64
#define XN 68

typedef __attribute__((ext_vector_type(8))) short bf16x8;
typedef __attribute__((ext_vector_type(4))) float f32x4;

__device__ inline short f2bf(float f) {
  union { __hip_bfloat16 h; unsigned short u; } cv;
  cv.h = __float2bfloat16(f);
  return (short)cv.u;
}

__device__ inline bf16x8 cvt8(float4 a, float4 b) {
  bf16x8 r;
  r[0] = f2bf(a.x); r[1] = f2bf(a.y); r[2] = f2bf(a.z); r[3] = f2bf(a.w);
  r[4] = f2bf(b.x); r[5] = f2bf(b.y); r[6] = f2bf(b.z); r[7] = f2bf(b.w);
  return r;
}

__device__ inline bf16x8 cvt8s(float4 a, float4 b, float s) {
  bf16x8 r;
  r[0] = f2bf(a.x * s); r[1] = f2bf(a.y * s); r[2] = f2bf(a.z * s); r[3] = f2bf(a.w * s);
  r[4] = f2bf(b.x * s); r[5] = f2bf(b.y * s); r[6] = f2bf(b.z * s); r[7] = f2bf(b.w * s);
  return r;
}

// ---------------- K1: A row stats. grid (NB, 32), 16 rows/block ----------------
__global__ __launch_bounds__(256) void k1_rowstats(
    const float* __restrict__ A, float* __restrict__ mc, float* __restrict__ dg,
    float* __restrict__ pA, float* __restrict__ pD) {
  int b = blockIdx.x, ch = blockIdx.y;
  int t = threadIdx.x, w = t >> 6, lane = t & 63;
  int r0 = ch * 16;
  const float* Ab = A + (size_t)b * NN * NN;
  __shared__ float wsum[4];
  __shared__ float sD[16];
  float4 v0[4], v1[4];
#pragma unroll
  for (int m = 0; m < 4; ++m) {
    const float* rp = Ab + (size_t)(r0 + w * 4 + m) * NN;
    v0[m] = *(const float4*)(rp + lane * 4);
    v1[m] = *(const float4*)(rp + 256 + lane * 4);
  }
  float accR = 0.f;
#pragma unroll
  for (int m = 0; m < 4; ++m) {
    float s = (v0[m].x + v0[m].y) + (v0[m].z + v0[m].w) +
              (v1[m].x + v1[m].y) + (v1[m].z + v1[m].w);
#pragma unroll
    for (int off = 1; off < 64; off <<= 1) s += __shfl_xor(s, off, 64);
    if (lane == 0) mc[b * NN + r0 + w * 4 + m] = s * (1.0f / NN);
    accR += s;
  }
  if (lane == 0) wsum[w] = accR;
  if (t < 16) {
    float d = Ab[(size_t)(r0 + t) * NN + r0 + t];
    dg[b * NN + r0 + t] = d;
    sD[t] = d;
  }
  __syncthreads();
  if (t == 0) {
    pA[b * 32 + ch] = wsum[0] + wsum[1] + wsum[2] + wsum[3];
    float sd = 0.f;
#pragma unroll
    for (int k = 0; k < 16; ++k) sd += sD[k];
    pD[b * 32 + ch] = sd;
  }
}

// ---------------- K2: merged per-batch stats + colv + vplus + X1. grid (NB) ----------------
__global__ __launch_bounds__(512) void k2_merged(
    const float* __restrict__ X, const float* __restrict__ cf,
    const float* __restrict__ W1, const float* __restrict__ W2,
    const float* __restrict__ mc, const float* __restrict__ dg,
    const float* __restrict__ pA, const float* __restrict__ pD,
    float* __restrict__ vplus, float* __restrict__ colv,
    unsigned short* __restrict__ X1) {
  int b = blockIdx.x, t = threadIdx.x;
  int w = t >> 6, lane = t & 63;
  __shared__ float sX[NN][36];       // padded: row base 144B (16B aligned), col reads conflict-free
  __shared__ float sSv[NN];
  __shared__ float sMXp[16][32], sTCp[16][32];
  __shared__ float sWr[8][3];
  __shared__ float sc[69], mX[CI], tC[CI], sA1[CO];
  __shared__ float sS[6];  // 0:smd 1:sma 2:scst 3:ssum 4:ssmc 5:ssdg

  if (t < 69) sc[t] = cf[t];
  const float* Xb = X + (size_t)b * NN * CI;
  // phase 1: each thread owns row t (32 floats)
  float4 x4[8];
#pragma unroll
  for (int k = 0; k < 8; ++k) {
    x4[k] = *(const float4*)(Xb + (size_t)t * CI + k * 4);
    *(float4*)&sX[t][k * 4] = x4[k];
  }
  float mcj = mc[b * NN + t], dgj = dg[b * NN + t];
  __syncthreads();  // sX + sc ready
  float sv = 0.f;
#pragma unroll
  for (int k = 0; k < 8; ++k) {
    sv += sc[5 + k * 4] * x4[k].x + sc[6 + k * 4] * x4[k].y +
          sc[7 + k * 4] * x4[k].z + sc[8 + k * 4] * x4[k].w;
  }
  float svec = fmaf(sc[3], mcj, fmaf(sc[4], dgj, sv));
  sSv[t] = svec;
  float p1 = svec, p2 = svec * mcj, p3 = svec * dgj;
#pragma unroll
  for (int off = 1; off < 64; off <<= 1) {
    p1 += __shfl_xor(p1, off, 64);
    p2 += __shfl_xor(p2, off, 64);
    p3 += __shfl_xor(p3, off, 64);
  }
  if (lane == 0) { sWr[w][0] = p1; sWr[w][1] = p2; sWr[w][2] = p3; }
  __syncthreads();  // sSv ready
  // phase 2: column partial sums via LDS (rg = row-group of 32)
  {
    int c = lane & 31, rg = w * 2 + (lane >> 5);
    float s1 = 0.f, s2 = 0.f;
#pragma unroll
    for (int r = 0; r < 32; ++r) {
      int j = rg * 32 + r;
      float v = sX[j][c];
      s1 += v;
      s2 += sSv[j] * v;
    }
    sMXp[rg][c] = s1;
    sTCp[rg][c] = s2;
  }
  __syncthreads();
  if (t < 32) {
    float s1 = 0.f, s2 = 0.f;
#pragma unroll
    for (int g = 0; g < 16; ++g) { s1 += sMXp[g][t]; s2 += sTCp[g][t]; }
    mX[t] = s1 * (1.0f / NN);
    tC[t] = s2;
  } else if (t == 32) {
    float sA = 0.f, sD = 0.f;
#pragma unroll
    for (int k = 0; k < 32; ++k) { sA += pA[b * 32 + k]; sD += pD[b * 32 + k]; }
    sS[0] = sD * (1.0f / NN);
    sS[1] = sA * (1.0f / ((float)NN * (float)NN));
  } else if (t == 33) {
    float s1 = 0.f, s2 = 0.f, s3 = 0.f;
#pragma unroll
    for (int k = 0; k < 8; ++k) { s1 += sWr[k][0]; s2 += sWr[k][1]; s3 += sWr[k][2]; }
    sS[3] = s1; sS[4] = s2; sS[5] = s3;
  }
  __syncthreads();
  if (t == 0) {
    float s7 = 0.f;
#pragma unroll
    for (int c = 0; c < CI; ++c) s7 += sc[5 + CI + c] * mX[c];
    sS[2] = sc[1] * sS[1] + sc[2] * sS[0] + s7;
  }
  __syncthreads();
  // phase 3: vplus + colv/a1
  vplus[b * NN + t] = sSv[t] + sS[2];
  if (t < CO) {
    int o = t;
    const float* w1 = W1 + o * XN;
    const float* w2 = W2 + o * XN;
    float w1mX = 0.f, a1 = 0.f, a2 = 0.f, wt = 0.f;
#pragma unroll
    for (int c = 0; c < CI; ++c) {
      w1mX += w1[c] * mX[c];
      a1 += w1[CI + c] * mX[c];
      a2 += w2[CI + c] * mX[c];
      wt += w1[c] * tC[c];
    }
    float smd = sS[0], sma = sS[1];
    a1 += w1[66] * smd + w1[67] * sma;
    a2 += w2[66] * smd + w2[67] * sma;
    float we0 = w1[64], we1 = w1[65];
    float S1n = w1mX + a1 + we0 * sma + we1 * smd;
    float SVn = (wt + a1 * sS[3] + we0 * sS[4] + we1 * sS[5]) * (1.0f / NN);
    sA1[o] = a1;
    float4 cvv = make_float4(S1n, a2 + SVn, w2[64], w2[65]);
    *(float4*)&colv[(b * CO + o) * 4] = cvv;
  }
  __syncthreads();
  // phase 4: X1 via MFMA, X read from LDS. wave w owns rows w*64..w*64+63
  {
    int ra = lane & 15, kg = lane >> 4, g = lane >> 4;
    bf16x8 wfrag[4];
    float ao[4], e0[4], e1[4];
#pragma unroll
    for (int to = 0; to < 4; ++to) {
      int o = to * 16 + ra;
      const float* wp = W1 + o * XN + kg * 8;
      wfrag[to] = cvt8(*(const float4*)wp, *(const float4*)(wp + 4));
      ao[to] = sA1[o];
      e0[to] = W1[o * XN + 64];
      e1[to] = W1[o * XN + 65];
    }
#pragma unroll
    for (int jj = 0; jj < 4; ++jj) {
      int j0 = w * 64 + jj * 16;
      const float* xp = &sX[j0 + ra][kg * 8];
      bf16x8 xf = cvt8(*(const float4*)xp, *(const float4*)(xp + 4));
      float4 mcv = *(const float4*)&mc[b * NN + j0 + g * 4];
      float4 dgv = *(const float4*)&dg[b * NN + j0 + g * 4];
      float mcr[4] = {mcv.x, mcv.y, mcv.z, mcv.w};
      float dgr[4] = {dgv.x, dgv.y, dgv.z, dgv.w};
#pragma unroll
      for (int to = 0; to < 4; ++to) {
        f32x4 zero = {0.f, 0.f, 0.f, 0.f};
        f32x4 d = __builtin_amdgcn_mfma_f32_16x16x32_bf16(xf, wfrag[to], zero, 0, 0, 0);
        union { unsigned short u[4]; uint2 v; } pk;
#pragma unroll
        for (int r = 0; r < 4; ++r) {
          float val = d[r] + ao[to] + e0[to] * mcr[r] + e1[to] * dgr[r];
          pk.u[r] = (unsigned short)f2bf(val);
        }
        *(uint2*)(X1 + ((size_t)b * CO + to * 16 + ra) * NN + j0 + g * 4) = pk.v;
      }
    }
  }
}

// ---------------- K5: batched MFMA GEMM, K split across waves ----------------
__global__ __launch_bounds__(512) void k5_mfma(
    const float* __restrict__ A, const unsigned short* __restrict__ X1,
    const float* __restrict__ X, const float* __restrict__ W2,
    const float* __restrict__ vplus, const float* __restrict__ mc,
    const float* __restrict__ dg, const float* __restrict__ colv,
    const float* __restrict__ cf, float* __restrict__ out) {
  int b = blockIdx.x, ic = blockIdx.y;
  int t = threadIdx.x, w = t >> 6, lane = t & 63;
  int ia = w & 1, q = w >> 1;
  int ra = lane & 15, kg = lane >> 4, g = lane >> 4;
  int i0 = ic * 32;
  __shared__ float sAcc[4 * 32 * 68];

  float c0n = cf[0] * (1.0f / NN);
  const float* Arow = A + ((size_t)(b * NN + i0 + ia * 16 + ra)) * NN;
  const unsigned short* X1b = X1 + (size_t)b * CO * NN;

  f32x4 acc[4] = {{0.f, 0.f, 0.f, 0.f}, {0.f, 0.f, 0.f, 0.f},
                  {0.f, 0.f, 0.f, 0.f}, {0.f, 0.f, 0.f, 0.f}};

#pragma unroll
  for (int jt = 0; jt < 4; ++jt) {
    int kb = q * 128 + jt * 32 + kg * 8;
    float4 a0 = *(const float4*)(Arow + kb);
    float4 a1 = *(const float4*)(Arow + kb + 4);
    bf16x8 af = cvt8s(a0, a1, c0n);
#pragma unroll
    for (int to = 0; to < 4; ++to) {
      bf16x8 bf = *(const bf16x8*)(X1b + (size_t)(to * 16 + ra) * NN + kb);
      acc[to] = __builtin_amdgcn_mfma_f32_16x16x32_bf16(af, bf, acc[to], 0, 0, 0);
    }
  }

  if (q == 0) {  // fused X*W2c k-step (unscaled)
    const float* xp = X + (size_t)(b * NN + i0 + ia * 16 + ra) * CI + kg * 8;
    bf16x8 xf = cvt8(*(const float4*)xp, *(const float4*)(xp + 4));
#pragma unroll
    for (int to = 0; to < 4; ++to) {
      const float* wp = W2 + (size_t)(to * 16 + ra) * XN + kg * 8;
      bf16x8 wf = cvt8(*(const float4*)wp, *(const float4*)(wp + 4));
      acc[to] = __builtin_amdgcn_mfma_f32_16x16x32_bf16(xf, wf, acc[to], 0, 0, 0);
    }
  }

  // epilogue prefetch: issue global loads BEFORE the LDS store + barrier so
  // their latency hides under the partial-reduce.
  int ei = t >> 4, eo4 = (t & 15) * 4;
  float e_vp = vplus[b * NN + i0 + ei];
  float e_mc = mc[b * NN + i0 + ei];
  float e_dg = dg[b * NN + i0 + ei];
  float4 cv0 = *(const float4*)&colv[(b * CO + eo4 + 0) * 4];
  float4 cv1 = *(const float4*)&colv[(b * CO + eo4 + 1) * 4];
  float4 cv2 = *(const float4*)&colv[(b * CO + eo4 + 2) * 4];
  float4 cv3 = *(const float4*)&colv[(b * CO + eo4 + 3) * 4];

#pragma unroll
  for (int to = 0; to < 4; ++to)
#pragma unroll
    for (int r = 0; r < 4; ++r)
      sAcc[(q * 32 + ia * 16 + g * 4 + r) * 68 + to * 16 + ra] = acc[to][r];
  __syncthreads();

  {
    f32x4 s = {0.f, 0.f, 0.f, 0.f};
#pragma unroll
    for (int qq = 0; qq < 4; ++qq) s += *(const f32x4*)&sAcc[(qq * 32 + ei) * 68 + eo4];
    float4 res;
    res.x = s[0] + e_vp * cv0.x + cv0.y + e_mc * cv0.z + e_dg * cv0.w;
    res.y = s[1] + e_vp * cv1.x + cv1.y + e_mc * cv1.z + e_dg * cv1.w;
    res.z = s[2] + e_vp * cv2.x + cv2.y + e_mc * cv2.z + e_dg * cv2.w;
    res.w = s[3] + e_vp * cv3.x + cv3.y + e_mc * cv3.z + e_dg * cv3.w;
    *(float4*)&out[((size_t)(b * NN + i0 + ei)) * CO + eo4] = res;
  }
}

extern "C" void kernel_launch(void* const* d_in, const int* in_sizes, int n_in,
                              void* d_out, int out_size, void* d_ws, size_t ws_size,
                              hipStream_t stream) {
  const float* A = (const float*)d_in[0];
  const float* X = (const float*)d_in[1];
  const float* cf = (const float*)d_in[2];
  const float* W1 = (const float*)d_in[3];
  const float* W2 = (const float*)d_in[4];
  float* out = (float*)d_out;

  float* p = (float*)d_ws;
  float* mc = p;      p += NB * NN;
  float* dg = p;      p += NB * NN;
  float* vplus = p;   p += NB * NN;
  float* pA = p;      p += NB * 32;
  float* pD = p;      p += NB * 32;
  float* colv = p;    p += NB * CO * 4;
  unsigned short* X1 = (unsigned short*)p;

  k1_rowstats<<<dim3(NB, 32), 256, 0, stream>>>(A, mc, dg, pA, pD);
  k2_merged<<<NB, 512, 0, stream>>>(X, cf, W1, W2, mc, dg, pA, pD,
                                    vplus, colv, X1);
  k5_mfma<<<dim3(NB, 16), 512, 0, stream>>>(A, X1, X, W2, vplus, mc, dg,
                                            colv, cf, out);
}